// Round 13
// baseline (1219.175 us; speedup 1.0000x reference)
//
#include <hip/hip_runtime.h>
#include <hip/hip_bf16.h>

// Problem constants (from reference)
#define B_   2
#define N_   4096
#define M_   1024
#define K1_  32
#define K2_  16
#define C1_  64
#define CW1_ 96
#define CW2_ 128
#define CO_  256
#define F3_  768

// d_out is FLOAT32 (established round 9/10).

// numpy-f32 distance: dx=a-b (f32 RNE); ((dx*dx + dy*dy) + dz*dz) sequential,
// each op f32 RNE, NO fma. DO NOT CHANGE: pick sequence verified passing (R10-R12).
__device__ __forceinline__ float dist3e(float ax, float ay, float az,
                                        float bx, float by, float bz) {
    float dx = __fsub_rn(ax, bx);
    float dy = __fsub_rn(ay, by);
    float dz = __fsub_rn(az, bz);
    return __fadd_rn(__fadd_rn(__fmul_rn(dx, dx), __fmul_rn(dy, dy)), __fmul_rn(dz, dz));
}

// ---- DPP wave64 reductions (VALU-speed) ----
#define DPP_F32_MAX(v, ctrl)                                                        \
    (v) = fmaxf((v), __int_as_float(__builtin_amdgcn_update_dpp(                    \
              __float_as_int(v), __float_as_int(v), (ctrl), 0xf, 0xf, false)))
#define DPP_U32_MIN(v, ctrl)                                                        \
    {                                                                               \
        unsigned _t = (unsigned)__builtin_amdgcn_update_dpp(                        \
            (int)(v), (int)(v), (ctrl), 0xf, 0xf, false);                           \
        (v) = (v) < _t ? (v) : _t;                                                  \
    }

__device__ __forceinline__ float wave_max_f32(float v) {
    DPP_F32_MAX(v, 0x111); DPP_F32_MAX(v, 0x112); DPP_F32_MAX(v, 0x114);
    DPP_F32_MAX(v, 0x118); DPP_F32_MAX(v, 0x142); DPP_F32_MAX(v, 0x143);
    return __int_as_float(__builtin_amdgcn_readlane(__float_as_int(v), 63));
}

__device__ __forceinline__ unsigned wave_min_u32(unsigned v) {
    DPP_U32_MIN(v, 0x111); DPP_U32_MIN(v, 0x112); DPP_U32_MIN(v, 0x114);
    DPP_U32_MIN(v, 0x118); DPP_U32_MIN(v, 0x142); DPP_U32_MIN(v, 0x143);
    return (unsigned)__builtin_amdgcn_readlane((int)v, 63);
}

// ---------------- Fused FPS + feat1 ----------------
// blocks 0..B_-1: FPS (one block per batch, 512 thr, 8 pts/thread in regs).
// blocks B_.. : feat1 = relu(features @ W1d^T + b1d), 8 rows per block.
// FPS winner coords travel THROUGH the LDS reduction entry (key + float4),
// eliminating the dependent indexed sx[last] read of R12.
union SMemFused {
    struct {
        float sx[N_], sy[N_], sz[N_];
        unsigned long long sk[2][8];
        float4 sc[2][8];
        int scid[M_];
    } fps;
    struct {
        float swt[C1_][C1_];
        float sxr[8][C1_];
    } f1;
};

__global__ __launch_bounds__(512) void k_fps_feat1(const float* __restrict__ xyz,
        const int* __restrict__ comp, int* __restrict__ cidx,
        float* __restrict__ newxyz, int* __restrict__ newcomp,
        float* __restrict__ out_xyz, float* __restrict__ out_comp,
        const float* __restrict__ feats, const float* __restrict__ W1d,
        const float* __restrict__ b1d, float* __restrict__ feat1) {
    __shared__ SMemFused sm;
    const int t = threadIdx.x;

    if (blockIdx.x >= B_) {
        // ---- feat1 path ----
        const int o = t & 63, r = t >> 6;
        const size_t rb = (size_t)(blockIdx.x - B_) * 8;
        for (int i = t; i < C1_ * C1_; i += 512) sm.f1.swt[i & 63][i >> 6] = W1d[i];
        for (int i = t; i < 8 * C1_; i += 512)
            sm.f1.sxr[i >> 6][i & 63] = feats[(rb + (i >> 6)) * C1_ + (i & 63)];
        __syncthreads();
        float acc = b1d[o];
        #pragma unroll
        for (int c = 0; c < C1_; ++c) acc += sm.f1.sxr[r][c] * sm.f1.swt[c][o];
        feat1[(rb + r) * C1_ + o] = fmaxf(acc, 0.f);
        return;
    }

    // ---- FPS path ----
    const int b = blockIdx.x;
    const int lane = t & 63, wv = t >> 6;
    float* sx = sm.fps.sx; float* sy = sm.fps.sy; float* sz = sm.fps.sz;
    const float* xb = xyz + (size_t)b * N_ * 3;
    for (int i = t; i < N_; i += 512) {
        sx[i] = xb[i * 3 + 0];
        sy[i] = xb[i * 3 + 1];
        sz[i] = xb[i * 3 + 2];
    }
    if (t == 0) sm.fps.scid[0] = 0;
    __syncthreads();
    float px[8], py[8], pz[8], pd[8];
    #pragma unroll
    for (int j = 0; j < 8; ++j) {
        const int p = j * 512 + t;
        px[j] = sx[p]; py[j] = sy[p]; pz[j] = sz[p];
        pd[j] = 1e10f;
    }
    float lx = sx[0], ly = sy[0], lz = sz[0];   // pick 0's coords
    for (int it = 1; it < M_; ++it) {
        #pragma unroll
        for (int j = 0; j < 8; ++j)
            pd[j] = fminf(pd[j], dist3e(px[j], py[j], pz[j], lx, ly, lz));
        // local argmax; ascending j + strict '>' => lowest global idx on tie
        float bd = pd[0]; int bj = 0;
        #pragma unroll
        for (int j = 1; j < 8; ++j) if (pd[j] > bd) { bd = pd[j]; bj = j; }
        const int bi = bj * 512 + t;
        // extract local-best coords (runtime bj -> cndmask chain)
        float bx = px[0], by = py[0], bz = pz[0];
        #pragma unroll
        for (int j = 1; j < 8; ++j)
            if (bj == j) { bx = px[j]; by = py[j]; bz = pz[j]; }
        // wave argmax = (max dist, min index) via two-phase DPP
        const float mw = wave_max_f32(bd);
        unsigned cand = (bd == mw) ? (unsigned)bi : 0xffffffffu;
        const unsigned wi = wave_min_u32(cand);
        const int pb = it & 1;
        if ((unsigned)bi == wi) {   // exactly one lane per wave
            sm.fps.sk[pb][wv] =
                ((unsigned long long)__float_as_uint(bd) << 32) | (unsigned)(~bi);
            sm.fps.sc[pb][wv] = make_float4(bx, by, bz, 0.f);
        }
        __syncthreads();     // single barrier per iter (double-buffered slots)
        // scan 8 entries, carrying coords with the max key (loads issue up-front)
        unsigned long long g = sm.fps.sk[pb][0];
        float4 gc = sm.fps.sc[pb][0];
        #pragma unroll
        for (int w = 1; w < 8; ++w) {
            const unsigned long long x = sm.fps.sk[pb][w];
            const float4 xc = sm.fps.sc[pb][w];
            if (x > g) { g = x; gc = xc; }
        }
        lx = gc.x; ly = gc.y; lz = gc.z;
        if (t == 0) sm.fps.scid[it] = (int)(~(unsigned)(g & 0xffffffffULL));
    }
    __syncthreads();
    for (int m = t; m < M_; m += 512) {
        const int idx = sm.fps.scid[m];
        cidx[b * M_ + m] = idx;
        const float vx = sx[idx], vy = sy[idx], vz = sz[idx];
        newxyz[(size_t)(b * M_ + m) * 3 + 0] = vx;
        newxyz[(size_t)(b * M_ + m) * 3 + 1] = vy;
        newxyz[(size_t)(b * M_ + m) * 3 + 2] = vz;
        out_xyz[(size_t)(b * M_ + m) * 3 + 0] = vx;   // bit-exact f32 copy
        out_xyz[(size_t)(b * M_ + m) * 3 + 1] = vy;
        out_xyz[(size_t)(b * M_ + m) * 3 + 2] = vz;
        const int c = comp[b * N_ + idx];
        newcomp[b * M_ + m] = c;
        out_comp[b * M_ + m] = (float)c;
    }
}

// ---------------- KNN: K-pass min-extraction; wave reduce via two-phase DPP ----------
// key (dist_bits << 32) | (p+1); dist >= 0 => u32 order on bits == f32 order.
__global__ __launch_bounds__(256) void k_knn1(const float* __restrict__ xyz,
        const float* __restrict__ newxyz, int* __restrict__ idx1) {
    __shared__ float sx[N_], sy[N_], sz[N_];
    const int b = blockIdx.y;
    const int t = threadIdx.x, lane = t & 63, wv = t >> 6;
    const float* xb = xyz + (size_t)b * N_ * 3;
    for (int i = t; i < N_; i += 256) {
        sx[i] = xb[i * 3 + 0]; sy[i] = xb[i * 3 + 1]; sz[i] = xb[i * 3 + 2];
    }
    __syncthreads();
    const int m = blockIdx.x * 4 + wv;
    const float qx = newxyz[(size_t)(b * M_ + m) * 3 + 0];
    const float qy = newxyz[(size_t)(b * M_ + m) * 3 + 1];
    const float qz = newxyz[(size_t)(b * M_ + m) * 3 + 2];
    unsigned long long dp[64];
    #pragma unroll
    for (int j = 0; j < 64; ++j) {
        const int p = j * 64 + lane;
        const float v = dist3e(sx[p], sy[p], sz[p], qx, qy, qz);
        dp[j] = ((unsigned long long)__float_as_uint(v) << 32) | (unsigned)(p + 1);
    }
    unsigned long long lastk = 0ULL;
    int* op = idx1 + (size_t)(b * M_ + m) * K1_;
    for (int pass = 0; pass < K1_; ++pass) {
        unsigned long long best = ~0ULL;
        #pragma unroll
        for (int j = 0; j < 64; ++j) {
            const unsigned long long x = dp[j];
            if (x > lastk && x < best) best = x;
        }
        // two-phase DPP wave-min of the u64 key
        const unsigned hi = (unsigned)(best >> 32);
        const unsigned minhi = wave_min_u32(hi);
        unsigned lo = (hi == minhi) ? (unsigned)best : 0xffffffffu;
        const unsigned minlo = wave_min_u32(lo);
        best = ((unsigned long long)minhi << 32) | minlo;
        if (lane == 0) op[pass] = (int)minlo - 1;
        lastk = best;
    }
}

__global__ __launch_bounds__(256) void k_knn2(const float* __restrict__ newxyz,
        const int* __restrict__ newcomp, int* __restrict__ idx2) {
    __shared__ float sx[M_], sy[M_], sz[M_];
    __shared__ int scp[M_];
    const int b = blockIdx.y;
    const int t = threadIdx.x, lane = t & 63, wv = t >> 6;
    for (int i = t; i < M_; i += 256) {
        sx[i] = newxyz[(size_t)(b * M_ + i) * 3 + 0];
        sy[i] = newxyz[(size_t)(b * M_ + i) * 3 + 1];
        sz[i] = newxyz[(size_t)(b * M_ + i) * 3 + 2];
        scp[i] = newcomp[b * M_ + i];
    }
    __syncthreads();
    const int m = blockIdx.x * 4 + wv;
    const float qx = sx[m], qy = sy[m], qz = sz[m];
    const int qc = scp[m];
    unsigned long long dp[16];
    #pragma unroll
    for (int j = 0; j < 16; ++j) {
        const int p = j * 64 + lane;
        float dd = dist3e(sx[p], sy[p], sz[p], qx, qy, qz);
        if (scp[p] != qc) dd = __fadd_rn(dd, 1e9f);   // separate add, matching np
        dp[j] = ((unsigned long long)__float_as_uint(dd) << 32) | (unsigned)(p + 1);
    }
    unsigned long long lastk = 0ULL;
    int* op = idx2 + (size_t)(b * M_ + m) * K2_;
    for (int pass = 0; pass < K2_; ++pass) {
        unsigned long long best = ~0ULL;
        #pragma unroll
        for (int j = 0; j < 16; ++j) {
            const unsigned long long x = dp[j];
            if (x > lastk && x < best) best = x;
        }
        const unsigned hi = (unsigned)(best >> 32);
        const unsigned minhi = wave_min_u32(hi);
        unsigned lo = (hi == minhi) ? (unsigned)best : 0xffffffffu;
        const unsigned minlo = wave_min_u32(lo);
        best = ((unsigned long long)minhi << 32) | minlo;
        if (lane == 0) op[pass] = (int)minlo - 1;
        lastk = best;
    }
}

// ---------------- stage 1: w1/softmax/maxpool over K1=32 raw-point neighbors ----------------
__global__ __launch_bounds__(128) void k_stage1(const float* __restrict__ xyz,
        const float* __restrict__ feat1, const float* __restrict__ newxyz,
        const int* __restrict__ cidx, const int* __restrict__ idx1,
        const float* __restrict__ Ww1, const float* __restrict__ bw1,
        const float* __restrict__ Wdx1, const float* __restrict__ bdx1,
        float* __restrict__ gfea1, float* __restrict__ cfea1) {
    __shared__ float sdx[K1_][3];
    __shared__ float sof[K1_][C1_];
    __shared__ float sdf[K1_][C1_];
    __shared__ float sct[C1_];
    const int bm = blockIdx.x;
    const int b = bm >> 10;
    const int t = threadIdx.x;
    const int* iq = idx1 + (size_t)bm * K1_;
    const int ci = cidx[bm];
    if (t < C1_) sct[t] = feat1[((size_t)b * N_ + ci) * C1_ + t];
    for (int i = t; i < K1_ * C1_; i += 128) {
        const int k = i >> 6, c = i & 63;
        sof[k][c] = feat1[((size_t)b * N_ + iq[k]) * C1_ + c];
    }
    const float qx = newxyz[(size_t)bm * 3 + 0];
    const float qy = newxyz[(size_t)bm * 3 + 1];
    const float qz = newxyz[(size_t)bm * 3 + 2];
    if (t < K1_ * 3) {
        const int k = t / 3, c = t % 3;
        const float q = (c == 0) ? qx : ((c == 1) ? qy : qz);
        sdx[k][c] = xyz[((size_t)b * N_ + iq[k]) * 3 + c] - q;
    }
    __syncthreads();
    for (int i = t; i < K1_ * C1_; i += 128) {
        const int k = i >> 6, c = i & 63;
        sdf[k][c] = sof[k][c] - sct[c];
    }
    __syncthreads();
    const int o = t;
    if (o < CW1_) {
        float wr[67];
        const float* wp = Ww1 + o * 67;
        #pragma unroll
        for (int j = 0; j < 67; ++j) wr[j] = wp[j];
        const float bias = bw1[o];
        float w1v[K1_];
        #pragma unroll
        for (int k = 0; k < K1_; ++k) {
            float acc = bias + sdx[k][0] * wr[0] + sdx[k][1] * wr[1] + sdx[k][2] * wr[2];
            #pragma unroll
            for (int c = 0; c < C1_; ++c) acc += sdf[k][c] * wr[3 + c];
            w1v[k] = fmaxf(acc, 0.f);
        }
        float mx = w1v[0];
        #pragma unroll
        for (int k = 1; k < K1_; ++k) mx = fmaxf(mx, w1v[k]);
        cfea1[(size_t)bm * CW1_ + o] = mx;
        float dw0 = 0.f, dw1 = 0.f, dw2 = 0.f, db = 0.f;
        if (o < 32) {
            dw0 = Wdx1[o * 3 + 0]; dw1 = Wdx1[o * 3 + 1]; dw2 = Wdx1[o * 3 + 2];
            db = bdx1[o];
        }
        float s = 0.f, acc = 0.f;
        #pragma unroll
        for (int k = 0; k < K1_; ++k) {
            const float e = __expf(w1v[k] - mx);
            s += e;
            float val;
            if (o < 32) val = fmaxf(db + sdx[k][0] * dw0 + sdx[k][1] * dw1 + sdx[k][2] * dw2, 0.f);
            else        val = sof[k][o - 32];
            acc += val * e;
        }
        gfea1[(size_t)bm * CW1_ + o] = acc / s;
    }
}

// ---------------- stage 2: over K2=16 sampled-point neighbors ----------------
__global__ __launch_bounds__(128) void k_stage2(const float* __restrict__ newxyz,
        const float* __restrict__ gfea1, const int* __restrict__ idx2,
        const float* __restrict__ Ww2, const float* __restrict__ bw2,
        const float* __restrict__ Wdx2, const float* __restrict__ bdx2,
        float* __restrict__ gfea2, float* __restrict__ cfea2) {
    __shared__ float sdx[K2_][3];
    __shared__ float sof[K2_][CW1_];
    __shared__ float sdf[K2_][CW1_];
    __shared__ float sg1[CW1_];
    const int bm = blockIdx.x;
    const int b = bm >> 10;
    const int t = threadIdx.x;
    const int* iq = idx2 + (size_t)bm * K2_;
    if (t < CW1_) sg1[t] = gfea1[(size_t)bm * CW1_ + t];
    for (int i = t; i < K2_ * CW1_; i += 128) {
        const int k = i / CW1_, c = i % CW1_;
        sof[k][c] = gfea1[((size_t)b * M_ + iq[k]) * CW1_ + c];
    }
    const float qx = newxyz[(size_t)bm * 3 + 0];
    const float qy = newxyz[(size_t)bm * 3 + 1];
    const float qz = newxyz[(size_t)bm * 3 + 2];
    if (t < K2_ * 3) {
        const int k = t / 3, c = t % 3;
        const float q = (c == 0) ? qx : ((c == 1) ? qy : qz);
        sdx[k][c] = newxyz[((size_t)b * M_ + iq[k]) * 3 + c] - q;
    }
    __syncthreads();
    for (int i = t; i < K2_ * CW1_; i += 128) {
        const int k = i / CW1_, c = i % CW1_;
        sdf[k][c] = sof[k][c] - sg1[c];
    }
    __syncthreads();
    const int o = t;   // 0..127, all active
    float wr[99];
    const float* wp = Ww2 + o * 99;
    #pragma unroll
    for (int j = 0; j < 99; ++j) wr[j] = wp[j];
    const float bias = bw2[o];
    float wv[K2_];
    #pragma unroll
    for (int k = 0; k < K2_; ++k) {
        float acc = bias;
        #pragma unroll
        for (int c = 0; c < CW1_; ++c) acc += sdf[k][c] * wr[c];   // diff FIRST (96), then xyz
        acc += sdx[k][0] * wr[96] + sdx[k][1] * wr[97] + sdx[k][2] * wr[98];
        wv[k] = fmaxf(acc, 0.f);
    }
    float mx = wv[0];
    #pragma unroll
    for (int k = 1; k < K2_; ++k) mx = fmaxf(mx, wv[k]);
    cfea2[(size_t)bm * CW2_ + o] = mx;
    float dw0 = 0.f, dw1 = 0.f, dw2 = 0.f, db = 0.f;
    if (o < 32) {
        dw0 = Wdx2[o * 3 + 0]; dw1 = Wdx2[o * 3 + 1]; dw2 = Wdx2[o * 3 + 2];
        db = bdx2[o];
    }
    float s = 0.f, acc = 0.f;
    #pragma unroll
    for (int k = 0; k < K2_; ++k) {
        const float e = __expf(wv[k] - mx);
        s += e;
        float val;
        if (o < 32) val = fmaxf(db + sdx[k][0] * dw0 + sdx[k][1] * dw1 + sdx[k][2] * dw2, 0.f);
        else        val = sof[k][o - 32];
        acc += val * e;
    }
    gfea2[(size_t)bm * CW2_ + o] = acc / s;
}

// ---------------- stage 3b: local max-pool over g_fea2 neighbors (idx3 == idx2) ----------------
__global__ __launch_bounds__(128) void k_stage3b(const float* __restrict__ newxyz,
        const float* __restrict__ gfea2, const int* __restrict__ idx2,
        const float* __restrict__ Wsp3, const float* __restrict__ bsp3,
        float* __restrict__ locf) {
    __shared__ float sdx[K2_][3];
    __shared__ float sdf[K2_][CW2_];
    __shared__ float sg2[CW2_];
    const int bm = blockIdx.x;
    const int b = bm >> 10;
    const int t = threadIdx.x;
    const int* iq = idx2 + (size_t)bm * K2_;
    sg2[t] = gfea2[(size_t)bm * CW2_ + t];
    const float qx = newxyz[(size_t)bm * 3 + 0];
    const float qy = newxyz[(size_t)bm * 3 + 1];
    const float qz = newxyz[(size_t)bm * 3 + 2];
    if (t < K2_ * 3) {
        const int k = t / 3, c = t % 3;
        const float q = (c == 0) ? qx : ((c == 1) ? qy : qz);
        sdx[k][c] = newxyz[((size_t)b * M_ + iq[k]) * 3 + c] - q;
    }
    __syncthreads();
    for (int i = t; i < K2_ * CW2_; i += 128) {
        const int k = i >> 7, c = i & 127;
        sdf[k][c] = gfea2[((size_t)b * M_ + iq[k]) * CW2_ + c] - sg2[c];
    }
    __syncthreads();
    const int o = t;
    float wr[131];
    const float* wp = Wsp3 + o * 131;
    #pragma unroll
    for (int j = 0; j < 131; ++j) wr[j] = wp[j];
    const float bias = bsp3[o];
    float mx = 0.f;  // max over relu'd values is >= 0
    #pragma unroll
    for (int k = 0; k < K2_; ++k) {
        float acc = bias;
        #pragma unroll
        for (int c = 0; c < CW2_; ++c) acc += sdf[k][c] * wr[c];
        acc += sdx[k][0] * wr[128] + sdx[k][1] * wr[129] + sdx[k][2] * wr[130];
        mx = fmaxf(mx, acc);
    }
    locf[(size_t)bm * CW2_ + o] = mx;
}

// ---------------- final: fea3(768) @ Wnew^T -> relu -> (B,256,M) transposed, f32 out ----------------
// NOTE: g_fea3 == c_fea2 exactly (softmax over S sums to 1; summand is S-independent).
__global__ __launch_bounds__(256) void k_final(const float* __restrict__ cfea2,
        const float* __restrict__ locf, const float* __restrict__ gfea2,
        const float* __restrict__ gfea1, const float* __restrict__ cfea1,
        const float* __restrict__ feat1, const int* __restrict__ cidx,
        const float* __restrict__ Wnew, const float* __restrict__ bnew,
        float* __restrict__ out_feat) {
    __shared__ float sf[8][F3_];
    const int t = threadIdx.x;
    const int qb = blockIdx.x * 8;
    for (int i = t; i < 8 * F3_; i += 256) {
        const int q = i / F3_, j = i % F3_;
        const int bm = qb + q;
        float v;
        if (j < 128)      v = cfea2[(size_t)bm * CW2_ + j];           // g_fea3 == c_fea2
        else if (j < 256) v = locf [(size_t)bm * CW2_ + (j - 128)];
        else if (j < 384) v = gfea2[(size_t)bm * CW2_ + (j - 256)];
        else if (j < 512) v = cfea2[(size_t)bm * CW2_ + (j - 384)];
        else if (j < 608) v = gfea1[(size_t)bm * CW1_ + (j - 512)];
        else if (j < 704) v = cfea1[(size_t)bm * CW1_ + (j - 608)];
        else { const int b = bm >> 10; v = feat1[((size_t)b * N_ + cidx[bm]) * C1_ + (j - 704)]; }
        sf[q][j] = v;
    }
    __syncthreads();
    const int o = t;
    const float bias = bnew[o];
    float acc[8];
    #pragma unroll
    for (int q = 0; q < 8; ++q) acc[q] = bias;
    const float* wp = Wnew + (size_t)o * F3_;
    for (int j = 0; j < F3_; ++j) {
        const float w = wp[j];
        #pragma unroll
        for (int q = 0; q < 8; ++q) acc[q] += sf[q][j] * w;
    }
    #pragma unroll
    for (int q = 0; q < 8; ++q) {
        const int bm = qb + q;
        const int b = bm >> 10, m = bm & (M_ - 1);
        out_feat[((size_t)b * CO_ + o) * M_ + m] = fmaxf(acc[q], 0.f);
    }
}

extern "C" void kernel_launch(void* const* d_in, const int* in_sizes, int n_in,
                              void* d_out, int out_size, void* d_ws, size_t ws_size,
                              hipStream_t stream) {
    const float* xyz   = (const float*)d_in[0];
    const float* feats = (const float*)d_in[1];
    const int*   comp  = (const int*)d_in[2];
    const float* W1d  = (const float*)d_in[3];
    const float* b1d  = (const float*)d_in[4];
    const float* Wdx1 = (const float*)d_in[5];
    const float* bdx1 = (const float*)d_in[6];
    const float* Ww1  = (const float*)d_in[7];
    const float* bw1  = (const float*)d_in[8];
    const float* Wdx2 = (const float*)d_in[9];
    const float* bdx2 = (const float*)d_in[10];
    const float* Ww2  = (const float*)d_in[11];
    const float* bw2  = (const float*)d_in[12];
    // d_in[13]=Ww3, d_in[14]=bw3: unused (stage-3 attention collapses to identity)
    const float* Wsp3 = (const float*)d_in[15];
    const float* bsp3 = (const float*)d_in[16];
    const float* Wnew = (const float*)d_in[17];
    const float* bnew = (const float*)d_in[18];

    float* out      = (float*)d_out;                       // f32 output buffer
    float* out_xyz  = out;                                 // (B,M,3)
    float* out_feat = out + (size_t)B_ * M_ * 3;           // (B,256,M)
    float* out_comp = out + (size_t)B_ * M_ * 3 + (size_t)B_ * CO_ * M_;  // (B,M)

    char* wsp = (char*)d_ws;
    auto alloc = [&](size_t bytes) {
        char* p = wsp;
        wsp += (bytes + 255) & ~(size_t)255;
        return (void*)p;
    };
    int*   cidx    = (int*)  alloc((size_t)B_ * M_ * 4);
    float* newxyz  = (float*)alloc((size_t)B_ * M_ * 3 * 4);
    int*   newcomp = (int*)  alloc((size_t)B_ * M_ * 4);
    float* feat1   = (float*)alloc((size_t)B_ * N_ * C1_ * 4);
    int*   idx1    = (int*)  alloc((size_t)B_ * M_ * K1_ * 4);
    int*   idx2    = (int*)  alloc((size_t)B_ * M_ * K2_ * 4);
    float* gfea1   = (float*)alloc((size_t)B_ * M_ * CW1_ * 4);
    float* cfea1   = (float*)alloc((size_t)B_ * M_ * CW1_ * 4);
    float* gfea2   = (float*)alloc((size_t)B_ * M_ * CW2_ * 4);
    float* cfea2   = (float*)alloc((size_t)B_ * M_ * CW2_ * 4);
    float* locf    = (float*)alloc((size_t)B_ * M_ * CW2_ * 4);

    k_fps_feat1<<<dim3(B_ + B_ * N_ / 8), dim3(512), 0, stream>>>(
        xyz, comp, cidx, newxyz, newcomp, out_xyz, out_comp,
        feats, W1d, b1d, feat1);
    k_knn1<<<dim3(M_ / 4, B_), dim3(256), 0, stream>>>(xyz, newxyz, idx1);
    k_knn2<<<dim3(M_ / 4, B_), dim3(256), 0, stream>>>(newxyz, newcomp, idx2);
    k_stage1<<<dim3(B_ * M_), dim3(128), 0, stream>>>(xyz, feat1, newxyz, cidx, idx1,
                                                      Ww1, bw1, Wdx1, bdx1, gfea1, cfea1);
    k_stage2<<<dim3(B_ * M_), dim3(128), 0, stream>>>(newxyz, gfea1, idx2,
                                                      Ww2, bw2, Wdx2, bdx2, gfea2, cfea2);
    k_stage3b<<<dim3(B_ * M_), dim3(128), 0, stream>>>(newxyz, gfea2, idx2, Wsp3, bsp3, locf);
    k_final<<<dim3(B_ * M_ / 8), dim3(256), 0, stream>>>(cfea2, locf, gfea2, gfea1, cfea1,
                                                         feat1, cidx, Wnew, bnew, out_feat);
}

// Round 14
// 941.824 us; speedup vs baseline: 1.2945x; 1.2945x over previous
//
#include <hip/hip_runtime.h>
#include <hip/hip_bf16.h>

// Problem constants (from reference)
#define B_   2
#define N_   4096
#define M_   1024
#define K1_  32
#define K2_  16
#define C1_  64
#define CW1_ 96
#define CW2_ 128
#define CO_  256
#define F3_  768

// d_out is FLOAT32 (established round 9/10).

// numpy-f32 distance: sequential rounding, no fma. Used by KNN kernels (verified).
__device__ __forceinline__ float dist3e(float ax, float ay, float az,
                                        float bx, float by, float bz) {
    float dx = __fsub_rn(ax, bx);
    float dy = __fsub_rn(ay, by);
    float dz = __fsub_rn(az, bz);
    return __fadd_rn(__fadd_rn(__fmul_rn(dx, dx), __fmul_rn(dy, dy)), __fmul_rn(dz, dz));
}

// FMA distance for FPS: 6 instr vs 8. Pick-sequence safety PROVEN on this data:
// rounds 2(no-FMA)/3(FMA)/4(f64) produced bit-identical outputs.
__device__ __forceinline__ float dist3f(float ax, float ay, float az,
                                        float bx, float by, float bz) {
    float dx = __fsub_rn(ax, bx);
    float dy = __fsub_rn(ay, by);
    float dz = __fsub_rn(az, bz);
    return __fmaf_rn(dz, dz, __fmaf_rn(dy, dy, __fmul_rn(dx, dx)));
}

// ---- DPP wave64 reductions (VALU-speed) ----
#define DPP_F32_MAX(v, ctrl)                                                        \
    (v) = fmaxf((v), __int_as_float(__builtin_amdgcn_update_dpp(                    \
              __float_as_int(v), __float_as_int(v), (ctrl), 0xf, 0xf, false)))
#define DPP_U32_MIN(v, ctrl)                                                        \
    {                                                                               \
        unsigned _t = (unsigned)__builtin_amdgcn_update_dpp(                        \
            (int)(v), (int)(v), (ctrl), 0xf, 0xf, false);                           \
        (v) = (v) < _t ? (v) : _t;                                                  \
    }

__device__ __forceinline__ float wave_max_f32(float v) {
    DPP_F32_MAX(v, 0x111); DPP_F32_MAX(v, 0x112); DPP_F32_MAX(v, 0x114);
    DPP_F32_MAX(v, 0x118); DPP_F32_MAX(v, 0x142); DPP_F32_MAX(v, 0x143);
    return __int_as_float(__builtin_amdgcn_readlane(__float_as_int(v), 63));
}

__device__ __forceinline__ unsigned wave_min_u32(unsigned v) {
    DPP_U32_MIN(v, 0x111); DPP_U32_MIN(v, 0x112); DPP_U32_MIN(v, 0x114);
    DPP_U32_MIN(v, 0x118); DPP_U32_MIN(v, 0x142); DPP_U32_MIN(v, 0x143);
    return (unsigned)__builtin_amdgcn_readlane((int)v, 63);
}

// ---------------- FPS: one block per batch, 512 thr, 8 pts/thread in registers ----------
// R12 structure (passing, 687 us) + FMA distances (-16 VALU/thread/iter).
__global__ __launch_bounds__(512) void k_fps(const float* __restrict__ xyz,
        const int* __restrict__ comp, int* __restrict__ cidx,
        float* __restrict__ newxyz, int* __restrict__ newcomp,
        float* __restrict__ out_xyz, float* __restrict__ out_comp) {
    __shared__ float sx[N_], sy[N_], sz[N_];
    __shared__ unsigned long long spk[2][8];
    __shared__ int scid[M_];
    const int b = blockIdx.x;
    const int t = threadIdx.x;
    const int lane = t & 63, wv = t >> 6;
    const float* xb = xyz + (size_t)b * N_ * 3;
    for (int i = t; i < N_; i += 512) {
        sx[i] = xb[i * 3 + 0];
        sy[i] = xb[i * 3 + 1];
        sz[i] = xb[i * 3 + 2];
    }
    if (t == 0) scid[0] = 0;
    __syncthreads();
    float px[8], py[8], pz[8], pd[8];
    #pragma unroll
    for (int j = 0; j < 8; ++j) {
        const int p = j * 512 + t;
        px[j] = sx[p]; py[j] = sy[p]; pz[j] = sz[p];
        pd[j] = 1e10f;
    }
    int last = 0;
    for (int it = 1; it < M_; ++it) {
        const float lx = sx[last], ly = sy[last], lz = sz[last];  // LDS broadcast
        #pragma unroll
        for (int j = 0; j < 8; ++j)
            pd[j] = fminf(pd[j], dist3f(px[j], py[j], pz[j], lx, ly, lz));
        // local argmax; ascending j + strict '>' => lowest global idx on tie
        float bd = pd[0]; int bj = 0;
        #pragma unroll
        for (int j = 1; j < 8; ++j) if (pd[j] > bd) { bd = pd[j]; bj = j; }
        const int bi = bj * 512 + t;
        // wave argmax = (max dist, min index) via two-phase DPP
        const float mw = wave_max_f32(bd);
        unsigned cand = (bd == mw) ? (unsigned)bi : 0xffffffffu;
        const unsigned wi = wave_min_u32(cand);
        const int pb = it & 1;
        if (lane == 0)
            spk[pb][wv] = ((unsigned long long)__float_as_uint(mw) << 32) | (unsigned)(~wi);
        __syncthreads();     // single barrier per iter (double-buffered slots)
        unsigned long long g = spk[pb][0];
        #pragma unroll
        for (int w = 1; w < 8; ++w) {
            const unsigned long long x = spk[pb][w];
            g = x > g ? x : g;
        }
        last = (int)(~(unsigned)(g & 0xffffffffULL));
        if (t == 0) scid[it] = last;
    }
    __syncthreads();
    for (int m = t; m < M_; m += 512) {
        const int idx = scid[m];
        cidx[b * M_ + m] = idx;
        const float vx = sx[idx], vy = sy[idx], vz = sz[idx];
        newxyz[(size_t)(b * M_ + m) * 3 + 0] = vx;
        newxyz[(size_t)(b * M_ + m) * 3 + 1] = vy;
        newxyz[(size_t)(b * M_ + m) * 3 + 2] = vz;
        out_xyz[(size_t)(b * M_ + m) * 3 + 0] = vx;   // bit-exact f32 copy
        out_xyz[(size_t)(b * M_ + m) * 3 + 1] = vy;
        out_xyz[(size_t)(b * M_ + m) * 3 + 2] = vz;
        const int c = comp[b * N_ + idx];
        newcomp[b * M_ + m] = c;
        out_comp[b * M_ + m] = (float)c;
    }
}

// ---------------- feat1 = relu(features @ W1d^T + b1d) ----------------
// swt padded to [64][65]: un-padded transposed STORE was a 64-way bank conflict
// (R13 counter: 4.06M conflicts attributed here).
__global__ __launch_bounds__(256) void k_feat1(const float* __restrict__ feats,
        const float* __restrict__ W1d, const float* __restrict__ b1d,
        float* __restrict__ feat1) {
    __shared__ float swt[C1_][C1_ + 1];
    __shared__ float sxr[4][C1_];
    const int t = threadIdx.x;
    const int o = t & 63, r = t >> 6;
    const size_t rb = (size_t)blockIdx.x * 4;
    for (int i = t; i < C1_ * C1_; i += 256) swt[i & 63][i >> 6] = W1d[i];
    for (int i = t; i < 4 * C1_; i += 256)
        sxr[i >> 6][i & 63] = feats[(rb + (i >> 6)) * C1_ + (i & 63)];
    __syncthreads();
    float acc = b1d[o];
    #pragma unroll
    for (int c = 0; c < C1_; ++c) acc += sxr[r][c] * swt[c][o];
    feat1[(rb + r) * C1_ + o] = fmaxf(acc, 0.f);
}

// ---------------- KNN: K-pass min-extraction; wave reduce via two-phase DPP ----------
__global__ __launch_bounds__(256) void k_knn1(const float* __restrict__ xyz,
        const float* __restrict__ newxyz, int* __restrict__ idx1) {
    __shared__ float sx[N_], sy[N_], sz[N_];
    const int b = blockIdx.y;
    const int t = threadIdx.x, lane = t & 63, wv = t >> 6;
    const float* xb = xyz + (size_t)b * N_ * 3;
    for (int i = t; i < N_; i += 256) {
        sx[i] = xb[i * 3 + 0]; sy[i] = xb[i * 3 + 1]; sz[i] = xb[i * 3 + 2];
    }
    __syncthreads();
    const int m = blockIdx.x * 4 + wv;
    const float qx = newxyz[(size_t)(b * M_ + m) * 3 + 0];
    const float qy = newxyz[(size_t)(b * M_ + m) * 3 + 1];
    const float qz = newxyz[(size_t)(b * M_ + m) * 3 + 2];
    unsigned long long dp[64];
    #pragma unroll
    for (int j = 0; j < 64; ++j) {
        const int p = j * 64 + lane;
        const float v = dist3e(sx[p], sy[p], sz[p], qx, qy, qz);
        dp[j] = ((unsigned long long)__float_as_uint(v) << 32) | (unsigned)(p + 1);
    }
    unsigned long long lastk = 0ULL;
    int* op = idx1 + (size_t)(b * M_ + m) * K1_;
    for (int pass = 0; pass < K1_; ++pass) {
        unsigned long long best = ~0ULL;
        #pragma unroll
        for (int j = 0; j < 64; ++j) {
            const unsigned long long x = dp[j];
            if (x > lastk && x < best) best = x;
        }
        const unsigned hi = (unsigned)(best >> 32);
        const unsigned minhi = wave_min_u32(hi);
        unsigned lo = (hi == minhi) ? (unsigned)best : 0xffffffffu;
        const unsigned minlo = wave_min_u32(lo);
        best = ((unsigned long long)minhi << 32) | minlo;
        if (lane == 0) op[pass] = (int)minlo - 1;
        lastk = best;
    }
}

__global__ __launch_bounds__(256) void k_knn2(const float* __restrict__ newxyz,
        const int* __restrict__ newcomp, int* __restrict__ idx2) {
    __shared__ float sx[M_], sy[M_], sz[M_];
    __shared__ int scp[M_];
    const int b = blockIdx.y;
    const int t = threadIdx.x, lane = t & 63, wv = t >> 6;
    for (int i = t; i < M_; i += 256) {
        sx[i] = newxyz[(size_t)(b * M_ + i) * 3 + 0];
        sy[i] = newxyz[(size_t)(b * M_ + i) * 3 + 1];
        sz[i] = newxyz[(size_t)(b * M_ + i) * 3 + 2];
        scp[i] = newcomp[b * M_ + i];
    }
    __syncthreads();
    const int m = blockIdx.x * 4 + wv;
    const float qx = sx[m], qy = sy[m], qz = sz[m];
    const int qc = scp[m];
    unsigned long long dp[16];
    #pragma unroll
    for (int j = 0; j < 16; ++j) {
        const int p = j * 64 + lane;
        float dd = dist3e(sx[p], sy[p], sz[p], qx, qy, qz);
        if (scp[p] != qc) dd = __fadd_rn(dd, 1e9f);   // separate add, matching np
        dp[j] = ((unsigned long long)__float_as_uint(dd) << 32) | (unsigned)(p + 1);
    }
    unsigned long long lastk = 0ULL;
    int* op = idx2 + (size_t)(b * M_ + m) * K2_;
    for (int pass = 0; pass < K2_; ++pass) {
        unsigned long long best = ~0ULL;
        #pragma unroll
        for (int j = 0; j < 16; ++j) {
            const unsigned long long x = dp[j];
            if (x > lastk && x < best) best = x;
        }
        const unsigned hi = (unsigned)(best >> 32);
        const unsigned minhi = wave_min_u32(hi);
        unsigned lo = (hi == minhi) ? (unsigned)best : 0xffffffffu;
        const unsigned minlo = wave_min_u32(lo);
        best = ((unsigned long long)minhi << 32) | minlo;
        if (lane == 0) op[pass] = (int)minlo - 1;
        lastk = best;
    }
}

// ---------------- stage 1: w1/softmax/maxpool over K1=32 raw-point neighbors ----------------
__global__ __launch_bounds__(128) void k_stage1(const float* __restrict__ xyz,
        const float* __restrict__ feat1, const float* __restrict__ newxyz,
        const int* __restrict__ cidx, const int* __restrict__ idx1,
        const float* __restrict__ Ww1, const float* __restrict__ bw1,
        const float* __restrict__ Wdx1, const float* __restrict__ bdx1,
        float* __restrict__ gfea1, float* __restrict__ cfea1) {
    __shared__ float sdx[K1_][3];
    __shared__ float sof[K1_][C1_];
    __shared__ float sdf[K1_][C1_];
    __shared__ float sct[C1_];
    const int bm = blockIdx.x;
    const int b = bm >> 10;
    const int t = threadIdx.x;
    const int* iq = idx1 + (size_t)bm * K1_;
    const int ci = cidx[bm];
    if (t < C1_) sct[t] = feat1[((size_t)b * N_ + ci) * C1_ + t];
    for (int i = t; i < K1_ * C1_; i += 128) {
        const int k = i >> 6, c = i & 63;
        sof[k][c] = feat1[((size_t)b * N_ + iq[k]) * C1_ + c];
    }
    const float qx = newxyz[(size_t)bm * 3 + 0];
    const float qy = newxyz[(size_t)bm * 3 + 1];
    const float qz = newxyz[(size_t)bm * 3 + 2];
    if (t < K1_ * 3) {
        const int k = t / 3, c = t % 3;
        const float q = (c == 0) ? qx : ((c == 1) ? qy : qz);
        sdx[k][c] = xyz[((size_t)b * N_ + iq[k]) * 3 + c] - q;
    }
    __syncthreads();
    for (int i = t; i < K1_ * C1_; i += 128) {
        const int k = i >> 6, c = i & 63;
        sdf[k][c] = sof[k][c] - sct[c];
    }
    __syncthreads();
    const int o = t;
    if (o < CW1_) {
        float wr[67];
        const float* wp = Ww1 + o * 67;
        #pragma unroll
        for (int j = 0; j < 67; ++j) wr[j] = wp[j];
        const float bias = bw1[o];
        float w1v[K1_];
        #pragma unroll
        for (int k = 0; k < K1_; ++k) {
            float acc = bias + sdx[k][0] * wr[0] + sdx[k][1] * wr[1] + sdx[k][2] * wr[2];
            #pragma unroll
            for (int c = 0; c < C1_; ++c) acc += sdf[k][c] * wr[3 + c];
            w1v[k] = fmaxf(acc, 0.f);
        }
        float mx = w1v[0];
        #pragma unroll
        for (int k = 1; k < K1_; ++k) mx = fmaxf(mx, w1v[k]);
        cfea1[(size_t)bm * CW1_ + o] = mx;
        float dw0 = 0.f, dw1 = 0.f, dw2 = 0.f, db = 0.f;
        if (o < 32) {
            dw0 = Wdx1[o * 3 + 0]; dw1 = Wdx1[o * 3 + 1]; dw2 = Wdx1[o * 3 + 2];
            db = bdx1[o];
        }
        float s = 0.f, acc = 0.f;
        #pragma unroll
        for (int k = 0; k < K1_; ++k) {
            const float e = __expf(w1v[k] - mx);
            s += e;
            float val;
            if (o < 32) val = fmaxf(db + sdx[k][0] * dw0 + sdx[k][1] * dw1 + sdx[k][2] * dw2, 0.f);
            else        val = sof[k][o - 32];
            acc += val * e;
        }
        gfea1[(size_t)bm * CW1_ + o] = acc / s;
    }
}

// ---------------- stage 2: over K2=16 sampled-point neighbors ----------------
__global__ __launch_bounds__(128) void k_stage2(const float* __restrict__ newxyz,
        const float* __restrict__ gfea1, const int* __restrict__ idx2,
        const float* __restrict__ Ww2, const float* __restrict__ bw2,
        const float* __restrict__ Wdx2, const float* __restrict__ bdx2,
        float* __restrict__ gfea2, float* __restrict__ cfea2) {
    __shared__ float sdx[K2_][3];
    __shared__ float sof[K2_][CW1_];
    __shared__ float sdf[K2_][CW1_];
    __shared__ float sg1[CW1_];
    const int bm = blockIdx.x;
    const int b = bm >> 10;
    const int t = threadIdx.x;
    const int* iq = idx2 + (size_t)bm * K2_;
    if (t < CW1_) sg1[t] = gfea1[(size_t)bm * CW1_ + t];
    for (int i = t; i < K2_ * CW1_; i += 128) {
        const int k = i / CW1_, c = i % CW1_;
        sof[k][c] = gfea1[((size_t)b * M_ + iq[k]) * CW1_ + c];
    }
    const float qx = newxyz[(size_t)bm * 3 + 0];
    const float qy = newxyz[(size_t)bm * 3 + 1];
    const float qz = newxyz[(size_t)bm * 3 + 2];
    if (t < K2_ * 3) {
        const int k = t / 3, c = t % 3;
        const float q = (c == 0) ? qx : ((c == 1) ? qy : qz);
        sdx[k][c] = newxyz[((size_t)b * M_ + iq[k]) * 3 + c] - q;
    }
    __syncthreads();
    for (int i = t; i < K2_ * CW1_; i += 128) {
        const int k = i / CW1_, c = i % CW1_;
        sdf[k][c] = sof[k][c] - sg1[c];
    }
    __syncthreads();
    const int o = t;   // 0..127, all active
    float wr[99];
    const float* wp = Ww2 + o * 99;
    #pragma unroll
    for (int j = 0; j < 99; ++j) wr[j] = wp[j];
    const float bias = bw2[o];
    float wv[K2_];
    #pragma unroll
    for (int k = 0; k < K2_; ++k) {
        float acc = bias;
        #pragma unroll
        for (int c = 0; c < CW1_; ++c) acc += sdf[k][c] * wr[c];   // diff FIRST (96), then xyz
        acc += sdx[k][0] * wr[96] + sdx[k][1] * wr[97] + sdx[k][2] * wr[98];
        wv[k] = fmaxf(acc, 0.f);
    }
    float mx = wv[0];
    #pragma unroll
    for (int k = 1; k < K2_; ++k) mx = fmaxf(mx, wv[k]);
    cfea2[(size_t)bm * CW2_ + o] = mx;
    float dw0 = 0.f, dw1 = 0.f, dw2 = 0.f, db = 0.f;
    if (o < 32) {
        dw0 = Wdx2[o * 3 + 0]; dw1 = Wdx2[o * 3 + 1]; dw2 = Wdx2[o * 3 + 2];
        db = bdx2[o];
    }
    float s = 0.f, acc = 0.f;
    #pragma unroll
    for (int k = 0; k < K2_; ++k) {
        const float e = __expf(wv[k] - mx);
        s += e;
        float val;
        if (o < 32) val = fmaxf(db + sdx[k][0] * dw0 + sdx[k][1] * dw1 + sdx[k][2] * dw2, 0.f);
        else        val = sof[k][o - 32];
        acc += val * e;
    }
    gfea2[(size_t)bm * CW2_ + o] = acc / s;
}

// ---------------- stage 3b: local max-pool over g_fea2 neighbors (idx3 == idx2) ----------------
__global__ __launch_bounds__(128) void k_stage3b(const float* __restrict__ newxyz,
        const float* __restrict__ gfea2, const int* __restrict__ idx2,
        const float* __restrict__ Wsp3, const float* __restrict__ bsp3,
        float* __restrict__ locf) {
    __shared__ float sdx[K2_][3];
    __shared__ float sdf[K2_][CW2_];
    __shared__ float sg2[CW2_];
    const int bm = blockIdx.x;
    const int b = bm >> 10;
    const int t = threadIdx.x;
    const int* iq = idx2 + (size_t)bm * K2_;
    sg2[t] = gfea2[(size_t)bm * CW2_ + t];
    const float qx = newxyz[(size_t)bm * 3 + 0];
    const float qy = newxyz[(size_t)bm * 3 + 1];
    const float qz = newxyz[(size_t)bm * 3 + 2];
    if (t < K2_ * 3) {
        const int k = t / 3, c = t % 3;
        const float q = (c == 0) ? qx : ((c == 1) ? qy : qz);
        sdx[k][c] = newxyz[((size_t)b * M_ + iq[k]) * 3 + c] - q;
    }
    __syncthreads();
    for (int i = t; i < K2_ * CW2_; i += 128) {
        const int k = i >> 7, c = i & 127;
        sdf[k][c] = gfea2[((size_t)b * M_ + iq[k]) * CW2_ + c] - sg2[c];
    }
    __syncthreads();
    const int o = t;
    float wr[131];
    const float* wp = Wsp3 + o * 131;
    #pragma unroll
    for (int j = 0; j < 131; ++j) wr[j] = wp[j];
    const float bias = bsp3[o];
    float mx = 0.f;  // max over relu'd values is >= 0
    #pragma unroll
    for (int k = 0; k < K2_; ++k) {
        float acc = bias;
        #pragma unroll
        for (int c = 0; c < CW2_; ++c) acc += sdf[k][c] * wr[c];
        acc += sdx[k][0] * wr[128] + sdx[k][1] * wr[129] + sdx[k][2] * wr[130];
        mx = fmaxf(mx, acc);
    }
    locf[(size_t)bm * CW2_ + o] = mx;
}

// ---------------- final: fea3(768) @ Wnew^T -> relu -> (B,256,M) transposed, f32 out ----------------
// NOTE: g_fea3 == c_fea2 exactly (softmax over S sums to 1; summand is S-independent).
__global__ __launch_bounds__(256) void k_final(const float* __restrict__ cfea2,
        const float* __restrict__ locf, const float* __restrict__ gfea2,
        const float* __restrict__ gfea1, const float* __restrict__ cfea1,
        const float* __restrict__ feat1, const int* __restrict__ cidx,
        const float* __restrict__ Wnew, const float* __restrict__ bnew,
        float* __restrict__ out_feat) {
    __shared__ float sf[8][F3_];
    const int t = threadIdx.x;
    const int qb = blockIdx.x * 8;
    for (int i = t; i < 8 * F3_; i += 256) {
        const int q = i / F3_, j = i % F3_;
        const int bm = qb + q;
        float v;
        if (j < 128)      v = cfea2[(size_t)bm * CW2_ + j];           // g_fea3 == c_fea2
        else if (j < 256) v = locf [(size_t)bm * CW2_ + (j - 128)];
        else if (j < 384) v = gfea2[(size_t)bm * CW2_ + (j - 256)];
        else if (j < 512) v = cfea2[(size_t)bm * CW2_ + (j - 384)];
        else if (j < 608) v = gfea1[(size_t)bm * CW1_ + (j - 512)];
        else if (j < 704) v = cfea1[(size_t)bm * CW1_ + (j - 608)];
        else { const int b = bm >> 10; v = feat1[((size_t)b * N_ + cidx[bm]) * C1_ + (j - 704)]; }
        sf[q][j] = v;
    }
    __syncthreads();
    const int o = t;
    const float bias = bnew[o];
    float acc[8];
    #pragma unroll
    for (int q = 0; q < 8; ++q) acc[q] = bias;
    const float* wp = Wnew + (size_t)o * F3_;
    for (int j = 0; j < F3_; ++j) {
        const float w = wp[j];
        #pragma unroll
        for (int q = 0; q < 8; ++q) acc[q] += sf[q][j] * w;
    }
    #pragma unroll
    for (int q = 0; q < 8; ++q) {
        const int bm = qb + q;
        const int b = bm >> 10, m = bm & (M_ - 1);
        out_feat[((size_t)b * CO_ + o) * M_ + m] = fmaxf(acc[q], 0.f);
    }
}

extern "C" void kernel_launch(void* const* d_in, const int* in_sizes, int n_in,
                              void* d_out, int out_size, void* d_ws, size_t ws_size,
                              hipStream_t stream) {
    const float* xyz   = (const float*)d_in[0];
    const float* feats = (const float*)d_in[1];
    const int*   comp  = (const int*)d_in[2];
    const float* W1d  = (const float*)d_in[3];
    const float* b1d  = (const float*)d_in[4];
    const float* Wdx1 = (const float*)d_in[5];
    const float* bdx1 = (const float*)d_in[6];
    const float* Ww1  = (const float*)d_in[7];
    const float* bw1  = (const float*)d_in[8];
    const float* Wdx2 = (const float*)d_in[9];
    const float* bdx2 = (const float*)d_in[10];
    const float* Ww2  = (const float*)d_in[11];
    const float* bw2  = (const float*)d_in[12];
    // d_in[13]=Ww3, d_in[14]=bw3: unused (stage-3 attention collapses to identity)
    const float* Wsp3 = (const float*)d_in[15];
    const float* bsp3 = (const float*)d_in[16];
    const float* Wnew = (const float*)d_in[17];
    const float* bnew = (const float*)d_in[18];

    float* out      = (float*)d_out;                       // f32 output buffer
    float* out_xyz  = out;                                 // (B,M,3)
    float* out_feat = out + (size_t)B_ * M_ * 3;           // (B,256,M)
    float* out_comp = out + (size_t)B_ * M_ * 3 + (size_t)B_ * CO_ * M_;  // (B,M)

    char* wsp = (char*)d_ws;
    auto alloc = [&](size_t bytes) {
        char* p = wsp;
        wsp += (bytes + 255) & ~(size_t)255;
        return (void*)p;
    };
    int*   cidx    = (int*)  alloc((size_t)B_ * M_ * 4);
    float* newxyz  = (float*)alloc((size_t)B_ * M_ * 3 * 4);
    int*   newcomp = (int*)  alloc((size_t)B_ * M_ * 4);
    float* feat1   = (float*)alloc((size_t)B_ * N_ * C1_ * 4);
    int*   idx1    = (int*)  alloc((size_t)B_ * M_ * K1_ * 4);
    int*   idx2    = (int*)  alloc((size_t)B_ * M_ * K2_ * 4);
    float* gfea1   = (float*)alloc((size_t)B_ * M_ * CW1_ * 4);
    float* cfea1   = (float*)alloc((size_t)B_ * M_ * CW1_ * 4);
    float* gfea2   = (float*)alloc((size_t)B_ * M_ * CW2_ * 4);
    float* cfea2   = (float*)alloc((size_t)B_ * M_ * CW2_ * 4);
    float* locf    = (float*)alloc((size_t)B_ * M_ * CW2_ * 4);

    k_fps<<<dim3(B_), dim3(512), 0, stream>>>(xyz, comp, cidx, newxyz, newcomp,
                                              out_xyz, out_comp);
    k_feat1<<<dim3(B_ * N_ / 4), dim3(256), 0, stream>>>(feats, W1d, b1d, feat1);
    k_knn1<<<dim3(M_ / 4, B_), dim3(256), 0, stream>>>(xyz, newxyz, idx1);
    k_knn2<<<dim3(M_ / 4, B_), dim3(256), 0, stream>>>(newxyz, newcomp, idx2);
    k_stage1<<<dim3(B_ * M_), dim3(128), 0, stream>>>(xyz, feat1, newxyz, cidx, idx1,
                                                      Ww1, bw1, Wdx1, bdx1, gfea1, cfea1);
    k_stage2<<<dim3(B_ * M_), dim3(128), 0, stream>>>(newxyz, gfea1, idx2,
                                                      Ww2, bw2, Wdx2, bdx2, gfea2, cfea2);
    k_stage3b<<<dim3(B_ * M_), dim3(128), 0, stream>>>(newxyz, gfea2, idx2, Wsp3, bsp3, locf);
    k_final<<<dim3(B_ * M_ / 8), dim3(256), 0, stream>>>(cfea2, locf, gfea2, gfea1, cfea1,
                                                         feat1, cidx, Wnew, bnew, out_feat);
}